// Round 1
// baseline (48.654 us; speedup 1.0000x reference)
//
#include <hip/hip_runtime.h>

// AdjacencySmoothnessLoss: out = 0.1 * sum |a[i][j] - 0.25*(a[i-1][j]+a[i+1][j]+a[i][j-1]+a[i][j+1])|
// over interior i,j in [1, 8190]. a is 8192x8192 fp32.

#define N 8192
#define ROWS_PER_BLOCK 64
#define TPB 256
#define COL_BLOCKS (N / (4 * TPB))              // 8
#define ROW_BLOCKS ((N - 2 + ROWS_PER_BLOCK - 1) / ROWS_PER_BLOCK)  // 128
#define NUM_PARTIALS (COL_BLOCKS * ROW_BLOCKS)  // 1024

__global__ __launch_bounds__(TPB) void smooth_partial(const float* __restrict__ a,
                                                      float* __restrict__ partial) {
    const int tid  = threadIdx.x;
    const int lane = tid & 63;
    const int c0   = (blockIdx.x * TPB + tid) * 4;   // aligned float4 chunk start col
    const int r0   = 1 + blockIdx.y * ROWS_PER_BLOCK;
    const int r1   = min(r0 + ROWS_PER_BLOCK - 1, N - 2);

    // register-rotated rows: p = row r-1, c = row r, n = row r+1
    float4 p = *(const float4*)(a + (size_t)(r0 - 1) * N + c0);
    float4 c = *(const float4*)(a + (size_t)r0 * N + c0);

    float acc = 0.0f;

    for (int r = r0; r <= r1; ++r) {
        float4 n = *(const float4*)(a + (size_t)(r + 1) * N + c0);

        // horizontal neighbors of the chunk via cross-lane shuffle
        float left  = __shfl_up(c.w, 1);    // lane i-1's c.w == a[r][c0-1]
        float right = __shfl_down(c.x, 1);  // lane i+1's c.x == a[r][c0+4]
        if (lane == 0)  left  = (c0 > 0)      ? a[(size_t)r * N + c0 - 1] : 0.0f;
        if (lane == 63) right = (c0 + 4 < N)  ? a[(size_t)r * N + c0 + 4] : 0.0f;

        // element 0 (col c0): interior only if c0 >= 1
        if (c0 >= 1) {
            float d = c.x - 0.25f * (p.x + n.x + left + c.y);
            acc += fabsf(d);
        }
        // element 1 (col c0+1): always interior (1 <= c0+1 <= 8189)
        {
            float d = c.y - 0.25f * (p.y + n.y + c.x + c.z);
            acc += fabsf(d);
        }
        // element 2 (col c0+2): always interior
        {
            float d = c.z - 0.25f * (p.z + n.z + c.y + c.w);
            acc += fabsf(d);
        }
        // element 3 (col c0+3): interior only if c0+3 <= 8190
        if (c0 + 3 <= N - 2) {
            float d = c.w - 0.25f * (p.w + n.w + c.z + right);
            acc += fabsf(d);
        }

        p = c;
        c = n;
    }

    // wave64 shuffle reduce
    for (int off = 32; off; off >>= 1) acc += __shfl_down(acc, off);

    __shared__ float wsum[TPB / 64];
    if (lane == 0) wsum[tid >> 6] = acc;
    __syncthreads();
    if (tid == 0) {
        float s = 0.0f;
        #pragma unroll
        for (int w = 0; w < TPB / 64; ++w) s += wsum[w];
        partial[blockIdx.y * gridDim.x + blockIdx.x] = s;
    }
}

__global__ __launch_bounds__(256) void reduce_final(const float* __restrict__ partial,
                                                    int n, float* __restrict__ out) {
    __shared__ double sh[256];
    double s = 0.0;
    for (int i = threadIdx.x; i < n; i += 256) s += (double)partial[i];
    sh[threadIdx.x] = s;
    __syncthreads();
    for (int stride = 128; stride; stride >>= 1) {
        if (threadIdx.x < stride) sh[threadIdx.x] += sh[threadIdx.x + stride];
        __syncthreads();
    }
    if (threadIdx.x == 0) out[0] = (float)(0.1 * sh[0]);
}

extern "C" void kernel_launch(void* const* d_in, const int* in_sizes, int n_in,
                              void* d_out, int out_size, void* d_ws, size_t ws_size,
                              hipStream_t stream) {
    const float* a   = (const float*)d_in[0];
    float* out       = (float*)d_out;
    float* partial   = (float*)d_ws;   // NUM_PARTIALS floats (4 KiB)

    dim3 grid(COL_BLOCKS, ROW_BLOCKS);
    smooth_partial<<<grid, TPB, 0, stream>>>(a, partial);
    reduce_final<<<1, 256, 0, stream>>>(partial, NUM_PARTIALS, out);
}